// Round 1
// baseline (2863.470 us; speedup 1.0000x reference)
//
#include <hip/hip_runtime.h>
#include <hip/hip_bf16.h>
#include <math.h>

#define N_NODES 100000
#define N_EDGES 1600000
#define D_FEAT 128
#define HIDDEN 100
#define N_CLASSES 10

// ws layout (float offsets)
#define OFF_DEG   0
#define OFF_DINV  100000
#define OFF_CSUM  200000
#define OFF_S     300000
#define OFF_H1    300128
#define OFF_ACC1  (300128 + 10000000)
// total floats: 20,300,128  (~81.2 MB)

__global__ void init_ws_kernel(float* __restrict__ ws) {
    long long tid = (long long)blockIdx.x * blockDim.x + threadIdx.x;
    if (tid < (long long)N_NODES * HIDDEN) {
        ws[OFF_ACC1 + tid] = 0.0f;
    }
    if (tid < N_NODES) {
        ws[OFF_DEG + tid] = 1.0f;   // self-loop
        ws[OFF_CSUM + tid] = 0.0f;
    }
    if (tid < 128) {
        ws[OFF_S + tid] = 0.0f;
    }
}

__global__ void deg_scatter_kernel(const int* __restrict__ dst, float* __restrict__ deg) {
    int e = blockIdx.x * blockDim.x + threadIdx.x;
    if (e < N_EDGES) {
        atomicAdd(&deg[dst[e]], 1.0f);
    }
}

__global__ void dinv_kernel(const float* __restrict__ deg, float* __restrict__ dinv) {
    int v = blockIdx.x * blockDim.x + threadIdx.x;
    if (v < N_NODES) {
        dinv[v] = rsqrtf(deg[v]);  // deg >= 1 always (self-loop)
    }
}

__global__ void csum_scatter_kernel(const int* __restrict__ src, const int* __restrict__ dst,
                                    const float* __restrict__ dinv, float* __restrict__ csum) {
    int e = blockIdx.x * blockDim.x + threadIdx.x;
    if (e < N_EDGES) {
        atomicAdd(&csum[src[e]], dinv[dst[e]]);
    }
}

// h1[r][c] = sum_k x[r][k] * W1[k][c];  one block per row, 128 threads
__global__ void gemm_xw_kernel(const float* __restrict__ x, const float* __restrict__ W1,
                               float* __restrict__ h1) {
    __shared__ float xs[D_FEAT];
    int r = blockIdx.x;
    int t = threadIdx.x;
    xs[t] = x[(size_t)r * D_FEAT + t];
    __syncthreads();
    if (t < HIDDEN) {
        float s = 0.0f;
#pragma unroll
        for (int k = 0; k < D_FEAT; ++k) {
            s += xs[k] * W1[k * HIDDEN + t];
        }
        h1[(size_t)r * HIDDEN + t] = s;
    }
}

// One thread per (edge, float4-chunk of 100 features -> 25 chunks)
__global__ void edge_scatter_kernel(const int* __restrict__ src, const int* __restrict__ dst,
                                    const float* __restrict__ dinv, const float* __restrict__ h1,
                                    float* __restrict__ acc) {
    long long tid = (long long)blockIdx.x * blockDim.x + threadIdx.x;
    if (tid >= (long long)N_EDGES * 25) return;
    int e  = (int)(tid / 25);
    int c4 = (int)(tid % 25);
    int s = src[e];
    int d = dst[e];
    float w = dinv[s] * dinv[d];
    const float4 v = *(const float4*)(h1 + (size_t)s * HIDDEN + c4 * 4);
    float* p = acc + (size_t)d * HIDDEN + c4 * 4;
    atomicAdd(p + 0, w * v.x);
    atomicAdd(p + 1, w * v.y);
    atomicAdd(p + 2, w * v.z);
    atomicAdd(p + 3, w * v.w);
}

// Fused: out1 = acc + dinv^2*h1 + b1; t = relu(out1); S[f] += sum_v c[v]*t[v][f]
#define NODES_PER_BLOCK 128
__global__ void finalize_reduce_kernel(const float* __restrict__ acc, const float* __restrict__ h1,
                                       const float* __restrict__ dinv, const float* __restrict__ csum,
                                       const float* __restrict__ b1, float* __restrict__ S) {
    int f = threadIdx.x;  // 128 threads, f < HIDDEN active
    int base = blockIdx.x * NODES_PER_BLOCK;
    if (f < HIDDEN) {
        float bf = b1[f];
        float s = 0.0f;
        for (int i = 0; i < NODES_PER_BLOCK; ++i) {
            int v = base + i;
            if (v >= N_NODES) break;
            float dv = dinv[v];
            float cv = dv * (csum[v] + dv);
            float t = acc[(size_t)v * HIDDEN + f] + dv * dv * h1[(size_t)v * HIDDEN + f] + bf;
            t = fmaxf(t, 0.0f);
            s += cv * t;
        }
        atomicAdd(&S[f], s);
    }
}

// pooled[j] = (1/N) * sum_f S[f]*W2[f][j] + b2[j]; out = log_softmax(pooled)
__global__ void final_out_kernel(const float* __restrict__ S, const float* __restrict__ W2,
                                 const float* __restrict__ b2, float* __restrict__ out) {
    __shared__ float p[16];
    int j = threadIdx.x;
    if (j < N_CLASSES) {
        float s = 0.0f;
        for (int f = 0; f < HIDDEN; ++f) {
            s += S[f] * W2[f * N_CLASSES + j];
        }
        p[j] = s * (1.0f / (float)N_NODES) + b2[j];
    }
    __syncthreads();
    if (j == 0) {
        float m = -INFINITY;
        for (int i = 0; i < N_CLASSES; ++i) m = fmaxf(m, p[i]);
        float se = 0.0f;
        for (int i = 0; i < N_CLASSES; ++i) se += expf(p[i] - m);
        float ls = logf(se);
        for (int i = 0; i < N_CLASSES; ++i) out[i] = p[i] - m - ls;
    }
}

extern "C" void kernel_launch(void* const* d_in, const int* in_sizes, int n_in,
                              void* d_out, int out_size, void* d_ws, size_t ws_size,
                              hipStream_t stream) {
    const float* x   = (const float*)d_in[0];
    const int*   ei  = (const int*)d_in[1];   // [2][N_EDGES]: row0 = src, row1 = dst
    const float* W1  = (const float*)d_in[2];
    const float* b1  = (const float*)d_in[3];
    const float* W2  = (const float*)d_in[4];
    const float* b2  = (const float*)d_in[5];
    float* out = (float*)d_out;
    float* ws  = (float*)d_ws;

    const int* src = ei;
    const int* dst = ei + N_EDGES;

    float* deg  = ws + OFF_DEG;
    float* dinv = ws + OFF_DINV;
    float* csum = ws + OFF_CSUM;
    float* S    = ws + OFF_S;
    float* h1   = ws + OFF_H1;
    float* acc1 = ws + OFF_ACC1;

    // 1) init
    {
        long long total = (long long)N_NODES * HIDDEN;
        int blocks = (int)((total + 255) / 256);
        init_ws_kernel<<<blocks, 256, 0, stream>>>(ws);
    }
    // 2) degree scatter
    deg_scatter_kernel<<<(N_EDGES + 255) / 256, 256, 0, stream>>>(dst, deg);
    // 3) dinv
    dinv_kernel<<<(N_NODES + 255) / 256, 256, 0, stream>>>(deg, dinv);
    // 4) csum scatter (source-side normalization sums for collapsed layer 2)
    csum_scatter_kernel<<<(N_EDGES + 255) / 256, 256, 0, stream>>>(src, dst, dinv, csum);
    // 5) GEMM h1 = x @ W1
    gemm_xw_kernel<<<N_NODES, D_FEAT, 0, stream>>>(x, W1, h1);
    // 6) edge gather-scale-scatter
    {
        long long total = (long long)N_EDGES * 25;
        int blocks = (int)((total + 255) / 256);
        edge_scatter_kernel<<<blocks, 256, 0, stream>>>(src, dst, dinv, h1, acc1);
    }
    // 7) finalize + weighted reduce to S[100]
    {
        int blocks = (N_NODES + NODES_PER_BLOCK - 1) / NODES_PER_BLOCK;
        finalize_reduce_kernel<<<blocks, 128, 0, stream>>>(acc1, h1, dinv, csum, b1, S);
    }
    // 8) final matvec + log_softmax
    final_out_kernel<<<1, 64, 0, stream>>>(S, W2, b2, out);
}

// Round 2
// 745.231 us; speedup vs baseline: 3.8424x; 3.8424x over previous
//
#include <hip/hip_runtime.h>
#include <hip/hip_bf16.h>
#include <math.h>

#define N_NODES 100000
#define N_EDGES 1600000
#define D_FEAT 128
#define HIDDEN 100
#define N_CLASSES 10

#define SCAN_BLOCK 256
#define N_SCAN_BLOCKS ((N_NODES + SCAN_BLOCK - 1) / SCAN_BLOCK)  // 391

// ws layout (4-byte word offsets)
#define OFF_DEGI   0                         // int[N_NODES]
#define OFF_ROWPTR (OFF_DEGI + N_NODES)      // int[N_NODES+1]
#define OFF_CURSOR (OFF_ROWPTR + N_NODES + 1)// int[N_NODES]
#define OFF_BSUM   (OFF_CURSOR + N_NODES)    // int[N_SCAN_BLOCKS] (pad to 512)
#define OFF_DINV   (OFF_BSUM + 512)          // float[N_NODES]
#define OFF_CSUM   (OFF_DINV + N_NODES)      // float[N_NODES]
#define OFF_S      (OFF_CSUM + N_NODES)      // float[128]
#define OFF_CSRC   (OFF_S + 128)             // int[N_EDGES]
#define OFF_CSRW   (OFF_CSRC + N_EDGES)      // float[N_EDGES]
#define OFF_H1     (OFF_CSRW + N_EDGES)      // float[N_NODES*HIDDEN]
// total words ~ 0.5M + 3.2M + 10M  (~55 MB)

__global__ void k_init(int* __restrict__ deg_i, float* __restrict__ csum, float* __restrict__ S) {
    int i = blockIdx.x * blockDim.x + threadIdx.x;
    if (i < N_NODES) { deg_i[i] = 0; csum[i] = 0.0f; }
    if (i < 128) S[i] = 0.0f;
}

__global__ void k_deg(const int* __restrict__ dst, int* __restrict__ deg_i) {
    int e = blockIdx.x * blockDim.x + threadIdx.x;
    if (e < N_EDGES) atomicAdd(&deg_i[dst[e]], 1);
}

__global__ void k_dinv(const int* __restrict__ deg_i, float* __restrict__ dinv) {
    int v = blockIdx.x * blockDim.x + threadIdx.x;
    if (v < N_NODES) dinv[v] = rsqrtf((float)(deg_i[v] + 1));  // +1 = self-loop
}

__global__ void k_csum(const int* __restrict__ src, const int* __restrict__ dst,
                       const float* __restrict__ dinv, float* __restrict__ csum) {
    int e = blockIdx.x * blockDim.x + threadIdx.x;
    if (e < N_EDGES) atomicAdd(&csum[src[e]], dinv[dst[e]]);
}

// block-local exclusive scan of deg_i -> rowptr(local), block sums -> bsum
__global__ void k_scan1(const int* __restrict__ deg_i, int* __restrict__ rowptr,
                        int* __restrict__ bsum) {
    __shared__ int sh[SCAN_BLOCK];
    int t = threadIdx.x;
    int i = blockIdx.x * SCAN_BLOCK + t;
    int v = (i < N_NODES) ? deg_i[i] : 0;
    sh[t] = v;
    __syncthreads();
    for (int off = 1; off < SCAN_BLOCK; off <<= 1) {
        int a = (t >= off) ? sh[t - off] : 0;
        __syncthreads();
        sh[t] += a;
        __syncthreads();
    }
    if (i < N_NODES) rowptr[i] = sh[t] - v;  // exclusive (block-local)
    if (t == SCAN_BLOCK - 1) bsum[blockIdx.x] = sh[t];
}

__global__ void k_scan2(int* __restrict__ bsum, int* __restrict__ rowptr) {
    if (threadIdx.x == 0 && blockIdx.x == 0) {
        int run = 0;
        for (int i = 0; i < N_SCAN_BLOCKS; ++i) { int t = bsum[i]; bsum[i] = run; run += t; }
        rowptr[N_NODES] = run;  // == N_EDGES
    }
}

__global__ void k_scan3(int* __restrict__ rowptr, const int* __restrict__ bsum,
                        int* __restrict__ cursor) {
    int i = blockIdx.x * blockDim.x + threadIdx.x;
    if (i < N_NODES) {
        int r = rowptr[i] + bsum[i / SCAN_BLOCK];
        rowptr[i] = r;
        cursor[i] = r;
    }
}

__global__ void k_fill(const int* __restrict__ src, const int* __restrict__ dst,
                       const float* __restrict__ dinv, int* __restrict__ cursor,
                       int* __restrict__ csr_src, float* __restrict__ csr_w) {
    int e = blockIdx.x * blockDim.x + threadIdx.x;
    if (e < N_EDGES) {
        int s = src[e];
        int d = dst[e];
        int pos = atomicAdd(&cursor[d], 1);
        csr_src[pos] = s;
        csr_w[pos] = dinv[s];
    }
}

// h1[r][c] = sum_k x[r][k] * W1[k][c];  one block per row, 128 threads
__global__ void gemm_xw_kernel(const float* __restrict__ x, const float* __restrict__ W1,
                               float* __restrict__ h1) {
    __shared__ float xs[D_FEAT];
    int r = blockIdx.x;
    int t = threadIdx.x;
    xs[t] = x[(size_t)r * D_FEAT + t];
    __syncthreads();
    if (t < HIDDEN) {
        float s = 0.0f;
#pragma unroll
        for (int k = 0; k < D_FEAT; ++k) {
            s += xs[k] * W1[k * HIDDEN + t];
        }
        h1[(size_t)r * HIDDEN + t] = s;
    }
}

// CSR gather + fused finalize: per dst node, sum incoming messages in registers,
// add self-loop + bias, relu, weight by c[v], block-partial reduce into S[100].
#define NPB 64  // nodes per block
__global__ void k_gather(const int* __restrict__ rowptr, const int* __restrict__ csr_src,
                         const float* __restrict__ csr_w, const float* __restrict__ dinv,
                         const float* __restrict__ csum, const float* __restrict__ h1,
                         const float* __restrict__ b1, float* __restrict__ S) {
    int f = threadIdx.x;               // 128 threads
    int fc = (f < HIDDEN) ? f : (HIDDEN - 1);  // clamp: lanes >=100 shadow lane 99
    float bf = b1[fc];
    float sacc = 0.0f;
    int vbase = blockIdx.x * NPB;
    for (int i = 0; i < NPB; ++i) {
        int v = vbase + i;
        if (v >= N_NODES) break;
        float dv = dinv[v];
        int jb = rowptr[v];
        int je = rowptr[v + 1];
        float acc = dv * dv * h1[(size_t)v * HIDDEN + fc];  // self-loop term
        int j = jb;
        for (; j + 1 < je; j += 2) {
            int s0 = csr_src[j];
            int s1 = csr_src[j + 1];
            float w0 = csr_w[j] * dv;
            float w1 = csr_w[j + 1] * dv;
            acc += w0 * h1[(size_t)s0 * HIDDEN + fc];
            acc += w1 * h1[(size_t)s1 * HIDDEN + fc];
        }
        if (j < je) {
            int s0 = csr_src[j];
            acc += csr_w[j] * dv * h1[(size_t)s0 * HIDDEN + fc];
        }
        float t = fmaxf(acc + bf, 0.0f);
        float cv = dv * (csum[v] + dv);
        sacc += cv * t;
    }
    if (f < HIDDEN) atomicAdd(&S[f], sacc);
}

// pooled[j] = (1/N) * sum_f S[f]*W2[f][j] + b2[j]; out = log_softmax(pooled)
__global__ void final_out_kernel(const float* __restrict__ S, const float* __restrict__ W2,
                                 const float* __restrict__ b2, float* __restrict__ out) {
    __shared__ float p[16];
    int j = threadIdx.x;
    if (j < N_CLASSES) {
        float s = 0.0f;
        for (int f = 0; f < HIDDEN; ++f) {
            s += S[f] * W2[f * N_CLASSES + j];
        }
        p[j] = s * (1.0f / (float)N_NODES) + b2[j];
    }
    __syncthreads();
    if (j == 0) {
        float m = -INFINITY;
        for (int i = 0; i < N_CLASSES; ++i) m = fmaxf(m, p[i]);
        float se = 0.0f;
        for (int i = 0; i < N_CLASSES; ++i) se += expf(p[i] - m);
        float ls = logf(se);
        for (int i = 0; i < N_CLASSES; ++i) out[i] = p[i] - m - ls;
    }
}

extern "C" void kernel_launch(void* const* d_in, const int* in_sizes, int n_in,
                              void* d_out, int out_size, void* d_ws, size_t ws_size,
                              hipStream_t stream) {
    const float* x  = (const float*)d_in[0];
    const int*   ei = (const int*)d_in[1];   // [2][N_EDGES]: row0 = src, row1 = dst
    const float* W1 = (const float*)d_in[2];
    const float* b1 = (const float*)d_in[3];
    const float* W2 = (const float*)d_in[4];
    const float* b2 = (const float*)d_in[5];
    float* out = (float*)d_out;

    const int* src = ei;
    const int* dst = ei + N_EDGES;

    int*   wsi     = (int*)d_ws;
    float* wsf     = (float*)d_ws;
    int*   deg_i   = wsi + OFF_DEGI;
    int*   rowptr  = wsi + OFF_ROWPTR;
    int*   cursor  = wsi + OFF_CURSOR;
    int*   bsum    = wsi + OFF_BSUM;
    float* dinv    = wsf + OFF_DINV;
    float* csum    = wsf + OFF_CSUM;
    float* S       = wsf + OFF_S;
    int*   csr_src = wsi + OFF_CSRC;
    float* csr_w   = wsf + OFF_CSRW;
    float* h1      = wsf + OFF_H1;

    const int nodeBlocks = (N_NODES + 255) / 256;   // 391
    const int edgeBlocks = (N_EDGES + 255) / 256;   // 6250

    k_init<<<nodeBlocks, 256, 0, stream>>>(deg_i, csum, S);
    k_deg<<<edgeBlocks, 256, 0, stream>>>(dst, deg_i);
    k_dinv<<<nodeBlocks, 256, 0, stream>>>(deg_i, dinv);
    k_csum<<<edgeBlocks, 256, 0, stream>>>(src, dst, dinv, csum);

    k_scan1<<<N_SCAN_BLOCKS, SCAN_BLOCK, 0, stream>>>(deg_i, rowptr, bsum);
    k_scan2<<<1, 64, 0, stream>>>(bsum, rowptr);
    k_scan3<<<nodeBlocks, 256, 0, stream>>>(rowptr, bsum, cursor);
    k_fill<<<edgeBlocks, 256, 0, stream>>>(src, dst, dinv, cursor, csr_src, csr_w);

    gemm_xw_kernel<<<N_NODES, D_FEAT, 0, stream>>>(x, W1, h1);

    {
        int blocks = (N_NODES + NPB - 1) / NPB;  // 1563
        k_gather<<<blocks, 128, 0, stream>>>(rowptr, csr_src, csr_w, dinv, csum, h1, b1, S);
    }
    final_out_kernel<<<1, 64, 0, stream>>>(S, W2, b2, out);
}

// Round 3
// 422.795 us; speedup vs baseline: 6.7727x; 1.7626x over previous
//
#include <hip/hip_runtime.h>
#include <hip/hip_bf16.h>
#include <math.h>

#define N_NODES 100000
#define N_EDGES 1600000
#define D_FEAT 128
#define HIDDEN 100
#define N_CLASSES 10

#define SCAN_BLOCK 256
#define N_SCAN_BLOCKS ((N_NODES + SCAN_BLOCK - 1) / SCAN_BLOCK)  // 391

// ws layout (4-byte word offsets)
#define OFF_DEGI   0         // int[100000]
#define OFF_ROWPTR 100000    // int[100001]
#define OFF_CURSOR 200004    // int[100000]
#define OFF_BSUM   300004    // int[512]
#define OFF_DINV   300520    // float[100000]
#define OFF_CSUM   400520    // float[100000]
#define OFF_SPART  500520    // float[32*100]
#define OFF_CSRC   503720    // int[1600000]
#define OFF_H1B    2103720   // uint[100000*50]  (bf16x2 packed, row stride 50 uints = 100 cols)
// end: 7,103,720 words ~= 28.4 MB

__device__ inline unsigned pack_bf16x2(float a, float b) {
    unsigned ua = __float_as_uint(a); ua = (ua + 0x7FFFu + ((ua >> 16) & 1u)) >> 16;
    unsigned ub = __float_as_uint(b); ub = (ub + 0x7FFFu + ((ub >> 16) & 1u)) >> 16;
    return ua | (ub << 16);
}
__device__ inline float bf_lo(unsigned p) { return __uint_as_float(p << 16); }
__device__ inline float bf_hi(unsigned p) { return __uint_as_float(p & 0xFFFF0000u); }

__global__ void k_init(int* __restrict__ deg_i, float* __restrict__ csum, float* __restrict__ S_part) {
    int i = blockIdx.x * blockDim.x + threadIdx.x;
    if (i < N_NODES) { deg_i[i] = 0; csum[i] = 0.0f; }
    if (i < 32 * 100) S_part[i] = 0.0f;
}

__global__ void k_deg(const int* __restrict__ dst, int* __restrict__ deg_i) {
    int e = blockIdx.x * blockDim.x + threadIdx.x;
    if (e < N_EDGES) atomicAdd(&deg_i[dst[e]], 1);
}

__global__ void k_dinv(const int* __restrict__ deg_i, float* __restrict__ dinv) {
    int v = blockIdx.x * blockDim.x + threadIdx.x;
    if (v < N_NODES) dinv[v] = rsqrtf((float)(deg_i[v] + 1));  // +1 = self-loop
}

// block-local exclusive scan of deg_i -> rowptr(local), block sums -> bsum
__global__ void k_scan1(const int* __restrict__ deg_i, int* __restrict__ rowptr,
                        int* __restrict__ bsum) {
    __shared__ int sh[SCAN_BLOCK];
    int t = threadIdx.x;
    int i = blockIdx.x * SCAN_BLOCK + t;
    int v = (i < N_NODES) ? deg_i[i] : 0;
    sh[t] = v;
    __syncthreads();
    for (int off = 1; off < SCAN_BLOCK; off <<= 1) {
        int a = (t >= off) ? sh[t - off] : 0;
        __syncthreads();
        sh[t] += a;
        __syncthreads();
    }
    if (i < N_NODES) rowptr[i] = sh[t] - v;
    if (t == SCAN_BLOCK - 1) bsum[blockIdx.x] = sh[t];
}

__global__ void k_scan2(int* __restrict__ bsum, int* __restrict__ rowptr) {
    if (threadIdx.x == 0 && blockIdx.x == 0) {
        int run = 0;
        for (int i = 0; i < N_SCAN_BLOCKS; ++i) { int t = bsum[i]; bsum[i] = run; run += t; }
        rowptr[N_NODES] = run;
    }
}

__global__ void k_scan3(int* __restrict__ rowptr, const int* __restrict__ bsum,
                        int* __restrict__ cursor) {
    int i = blockIdx.x * blockDim.x + threadIdx.x;
    if (i < N_NODES) {
        int r = rowptr[i] + bsum[i / SCAN_BLOCK];
        rowptr[i] = r;
        cursor[i] = r;
    }
}

// fused: CSR bucket-fill by dst + csum[src] += dinv[dst]
__global__ void k_fill_csum(const int* __restrict__ src, const int* __restrict__ dst,
                            const float* __restrict__ dinv, int* __restrict__ cursor,
                            int* __restrict__ csr_src, float* __restrict__ csum) {
    int e = blockIdx.x * blockDim.x + threadIdx.x;
    if (e < N_EDGES) {
        int s = src[e];
        int d = dst[e];
        int pos = atomicAdd(&cursor[d], 1);
        csr_src[pos] = s;
        atomicAdd(&csum[s], dinv[d]);
    }
}

// h1 = x @ W1 -> bf16 packed. 32 rows/block, 4x4 register tile,
// xs in LDS (stride 130 breaks row-group bank collision), W1 via cached float4.
#define GROWS 32
__global__ __launch_bounds__(256) void k_gemm(const float* __restrict__ x,
                                              const float* __restrict__ W1,
                                              unsigned* __restrict__ h1b) {
    __shared__ float xs[GROWS * 130];
    int t = threadIdx.x;
    long long r0 = (long long)blockIdx.x * GROWS;
    for (int i = t; i < GROWS * D_FEAT; i += 256) {
        int r = i >> 7, k = i & 127;
        xs[r * 130 + k] = x[(r0 + r) * D_FEAT + k];
    }
    __syncthreads();
    if (t < 200) {
        int g = t % 25;   // col group: cols 4g..4g+3
        int rg = t / 25;  // row group: rows 4rg..4rg+3
        float acc[4][4];
#pragma unroll
        for (int a = 0; a < 4; ++a)
#pragma unroll
            for (int b = 0; b < 4; ++b) acc[a][b] = 0.0f;
        const float4* Wv = (const float4*)W1;  // float4 index: k*25 + g
        for (int k = 0; k < D_FEAT; k += 2) {
            float4 w0 = Wv[k * 25 + g];
            float4 w1 = Wv[(k + 1) * 25 + g];
#pragma unroll
            for (int rr = 0; rr < 4; ++rr) {
                float2 xv = *(const float2*)&xs[(rg * 4 + rr) * 130 + k];
                acc[rr][0] = fmaf(xv.x, w0.x, acc[rr][0]);
                acc[rr][1] = fmaf(xv.x, w0.y, acc[rr][1]);
                acc[rr][2] = fmaf(xv.x, w0.z, acc[rr][2]);
                acc[rr][3] = fmaf(xv.x, w0.w, acc[rr][3]);
                acc[rr][0] = fmaf(xv.y, w1.x, acc[rr][0]);
                acc[rr][1] = fmaf(xv.y, w1.y, acc[rr][1]);
                acc[rr][2] = fmaf(xv.y, w1.z, acc[rr][2]);
                acc[rr][3] = fmaf(xv.y, w1.w, acc[rr][3]);
            }
        }
#pragma unroll
        for (int rr = 0; rr < 4; ++rr) {
            long long row = r0 + rg * 4 + rr;
            uint2 pv;
            pv.x = pack_bf16x2(acc[rr][0], acc[rr][1]);
            pv.y = pack_bf16x2(acc[rr][2], acc[rr][3]);
            *(uint2*)&h1b[row * 50 + 2 * g] = pv;
        }
    }
}

// CSR gather in bf16 + fused relu/c-weight/partial reduce.
// 1 wave per NPW nodes; 50 active lanes, 2 features (bf16x2) per lane.
#define NPW 8
__global__ __launch_bounds__(128) void k_gather(const int* __restrict__ rowptr,
                                                const int* __restrict__ csr_src,
                                                const float* __restrict__ dinv,
                                                const float* __restrict__ csum,
                                                const unsigned* __restrict__ h1b,
                                                const float* __restrict__ b1,
                                                float* __restrict__ S_part) {
    int wave = threadIdx.x >> 6, lane = threadIdx.x & 63;
    int wid = blockIdx.x * 2 + wave;
    int u = (lane < 50) ? lane : 49;
    float2 bb = *(const float2*)&b1[2 * u];
    float s0 = 0.0f, s1 = 0.0f;
    int vbase = wid * NPW;  // grid exact: 6250 blocks * 2 waves * 8 = 100000
#pragma unroll 1
    for (int i = 0; i < NPW; ++i) {
        int v = vbase + i;
        float dv = dinv[v];
        int jb = rowptr[v], je = rowptr[v + 1];
        unsigned sp = h1b[(size_t)v * 50 + u];
        float a0 = 0.0f, a1 = 0.0f;  // sum of dinv[s]*h1[s] over in-edges
        int j = jb;
        for (; j + 1 < je; j += 2) {
            int sA = csr_src[j];
            int sB = csr_src[j + 1];
            float wA = dinv[sA];
            float wB = dinv[sB];
            unsigned pA = h1b[(size_t)sA * 50 + u];
            unsigned pB = h1b[(size_t)sB * 50 + u];
            a0 += wA * bf_lo(pA) + wB * bf_lo(pB);
            a1 += wA * bf_hi(pA) + wB * bf_hi(pB);
        }
        if (j < je) {
            int sA = csr_src[j];
            float wA = dinv[sA];
            unsigned pA = h1b[(size_t)sA * 50 + u];
            a0 += wA * bf_lo(pA);
            a1 += wA * bf_hi(pA);
        }
        float dv2 = dv * dv;
        float t0 = fmaxf(dv * a0 + dv2 * bf_lo(sp) + bb.x, 0.0f);
        float t1 = fmaxf(dv * a1 + dv2 * bf_hi(sp) + bb.y, 0.0f);
        float cv = dv * (csum[v] + dv);
        s0 += cv * t0;
        s1 += cv * t1;
    }
    if (lane < 50) {
        float* row = S_part + (wid & 31) * 100;
        atomicAdd(&row[2 * u], s0);
        atomicAdd(&row[2 * u + 1], s1);
    }
}

// reduce S_part -> S, matvec with W2, log_softmax
__global__ void k_final(const float* __restrict__ S_part, const float* __restrict__ W2,
                        const float* __restrict__ b2, float* __restrict__ out) {
    __shared__ float Sl[HIDDEN];
    __shared__ float p[16];
    int t = threadIdx.x;  // 128
    if (t < HIDDEN) {
        float s = 0.0f;
        for (int r = 0; r < 32; ++r) s += S_part[r * 100 + t];
        Sl[t] = s;
    }
    __syncthreads();
    if (t < N_CLASSES) {
        float s = 0.0f;
        for (int f = 0; f < HIDDEN; ++f) s += Sl[f] * W2[f * N_CLASSES + t];
        p[t] = s * (1.0f / (float)N_NODES) + b2[t];
    }
    __syncthreads();
    if (t == 0) {
        float m = -INFINITY;
        for (int i = 0; i < N_CLASSES; ++i) m = fmaxf(m, p[i]);
        float se = 0.0f;
        for (int i = 0; i < N_CLASSES; ++i) se += expf(p[i] - m);
        float ls = logf(se);
        for (int i = 0; i < N_CLASSES; ++i) out[i] = p[i] - m - ls;
    }
}

extern "C" void kernel_launch(void* const* d_in, const int* in_sizes, int n_in,
                              void* d_out, int out_size, void* d_ws, size_t ws_size,
                              hipStream_t stream) {
    const float* x  = (const float*)d_in[0];
    const int*   ei = (const int*)d_in[1];
    const float* W1 = (const float*)d_in[2];
    const float* b1 = (const float*)d_in[3];
    const float* W2 = (const float*)d_in[4];
    const float* b2 = (const float*)d_in[5];
    float* out = (float*)d_out;

    const int* src = ei;
    const int* dst = ei + N_EDGES;

    int*      wsi     = (int*)d_ws;
    float*    wsf     = (float*)d_ws;
    int*      deg_i   = wsi + OFF_DEGI;
    int*      rowptr  = wsi + OFF_ROWPTR;
    int*      cursor  = wsi + OFF_CURSOR;
    int*      bsum    = wsi + OFF_BSUM;
    float*    dinv    = wsf + OFF_DINV;
    float*    csum    = wsf + OFF_CSUM;
    float*    S_part  = wsf + OFF_SPART;
    int*      csr_src = wsi + OFF_CSRC;
    unsigned* h1b     = (unsigned*)(wsi + OFF_H1B);

    const int nodeBlocks = (N_NODES + 255) / 256;
    const int edgeBlocks = (N_EDGES + 255) / 256;

    k_init<<<nodeBlocks, 256, 0, stream>>>(deg_i, csum, S_part);
    k_deg<<<edgeBlocks, 256, 0, stream>>>(dst, deg_i);
    k_dinv<<<nodeBlocks, 256, 0, stream>>>(deg_i, dinv);

    k_scan1<<<N_SCAN_BLOCKS, SCAN_BLOCK, 0, stream>>>(deg_i, rowptr, bsum);
    k_scan2<<<1, 64, 0, stream>>>(bsum, rowptr);
    k_scan3<<<nodeBlocks, 256, 0, stream>>>(rowptr, bsum, cursor);
    k_fill_csum<<<edgeBlocks, 256, 0, stream>>>(src, dst, dinv, cursor, csr_src, csum);

    k_gemm<<<N_NODES / GROWS, 256, 0, stream>>>(x, W1, h1b);

    k_gather<<<N_NODES / (2 * NPW), 128, 0, stream>>>(rowptr, csr_src, dinv, csum, h1b, b1, S_part);
    k_final<<<1, 128, 0, stream>>>(S_part, W2, b2, out);
}